// Round 12
// baseline (682.842 us; speedup 1.0000x reference)
//
#include <hip/hip_runtime.h>
#include <math.h>

#define NN 8192
#define NPD 128
#define F_IN 128
#define DD 512
#define HH 1024
#define EE 131072
#define NDOC 64
#define NPAIR 32

typedef __attribute__((ext_vector_type(4))) float f32x4;
typedef __attribute__((ext_vector_type(4))) int i32x4;
typedef __attribute__((ext_vector_type(8))) int i32x8;
typedef const __attribute__((address_space(1))) void* gas_ptr;
typedef __attribute__((address_space(3))) void* las_ptr;

__device__ __forceinline__ unsigned char f2fp8(float f) {
    return (unsigned char)(__builtin_amdgcn_cvt_pk_fp8_f32(f, f, 0, false) & 0xff);
}

// ---------------------------------------------------------------------------
// Fused prep: x cast to fp8 (1024 blocks) + cnt zero (32) + all weight
// transposes K x M fp32 -> M x K fp8 (job table). fc2 pads M 32->128 zeros.
// ---------------------------------------------------------------------------
__global__ __launch_bounds__(256) void k_prep(
    const float* __restrict__ x, unsigned char* __restrict__ x8,
    int* __restrict__ cnt,
    const float* __restrict__ w_in, unsigned char* __restrict__ wt_in8,
    const float* __restrict__ w_mid, unsigned char* __restrict__ wt_mid8,
    const float* __restrict__ w_out, unsigned char* __restrict__ wt_out8,
    const float* __restrict__ fc1_w, unsigned char* __restrict__ wt_fc18,
    const float* __restrict__ fc2_w, unsigned char* __restrict__ wt_fc2p8,
    const float* __restrict__ qkv1_w, unsigned char* __restrict__ qkv1_8,
    const float* __restrict__ qkv2_w, unsigned char* __restrict__ qkv2_8,
    const float* __restrict__ qkv3_w, unsigned char* __restrict__ qkv3_8) {
    int b = blockIdx.x;
    const int tid = threadIdx.x;
    if (b < 1024) {  // cast x -> fp8
        int i = (b * 256 + tid) * 4;
        float4 v = *(const float4*)(x + i);
        unsigned lo = (unsigned)__builtin_amdgcn_cvt_pk_fp8_f32(v.x, v.y, 0, false) & 0xffffu;
        unsigned hi = (unsigned)__builtin_amdgcn_cvt_pk_fp8_f32(v.z, v.w, 0, false) & 0xffffu;
        *(unsigned*)(x8 + i) = lo | (hi << 16);
        return;
    }
    b -= 1024;
    if (b < 32) { cnt[b * 256 + tid] = 0; return; }
    b -= 32;
    const float* src; unsigned char* dst;
    int K, M, nx, ny, mreal; long sw = 0;
    if (b < 64)        {          src = w_in;   dst = wt_in8;   K = 128;  M = 512;  nx = 16; ny = 4;  mreal = 512; }
    else if (b < 320)  { b -= 64;   src = w_mid;  dst = wt_mid8;  K = 512;  M = 512;  nx = 16; ny = 16; mreal = 512; }
    else if (b < 576)  { b -= 320;  src = w_out;  dst = wt_out8;  K = 512;  M = 512;  nx = 16; ny = 16; mreal = 512; }
    else if (b < 832)  { b -= 576;  src = fc1_w;  dst = wt_fc18;  K = 512;  M = 512;  nx = 16; ny = 16; mreal = 512; }
    else if (b < 896)  { b -= 832;  src = fc2_w;  dst = wt_fc2p8; K = 512;  M = 32;   nx = 4;  ny = 16; mreal = 32; }
    else if (b < 2432) { b -= 896;  src = qkv1_w; dst = qkv1_8;   K = 512;  M = 1024; nx = 32; ny = 16; mreal = 1024; sw = 524288; }
    else if (b < 5504) { b -= 2432; src = qkv2_w; dst = qkv2_8;   K = 1024; M = 1024; nx = 32; ny = 32; mreal = 1024; sw = 1048576; }
    else               { b -= 5504; src = qkv3_w; dst = qkv3_8;   K = 1024; M = 512;  nx = 16; ny = 32; mreal = 512;  sw = 524288; }
    const int bx = (b % nx) * 32;
    const int rest = b / nx;
    const int by = (rest % ny) * 32;
    const int z = rest / ny;
    src += (size_t)z * sw;
    dst += (size_t)z * sw;
    __shared__ float t[32][33];
    const int tx = tid & 31, ty = tid >> 5;
    for (int i = ty; i < 32; i += 8)
        t[i][tx] = (bx + tx < mreal) ? src[(size_t)(by + i) * M + bx + tx] : 0.f;
    __syncthreads();
    for (int i = ty; i < 32; i += 8)
        dst[(size_t)(bx + i) * K + by + tx] = f2fp8(t[tx][i]);
}

// ---------------------------------------------------------------------------
// Degree / CSR construction
// ---------------------------------------------------------------------------
__global__ void k_count(const int* __restrict__ ei, int* __restrict__ cnt) {
    int e = blockIdx.x * 256 + threadIdx.x;
    if (e < EE) atomicAdd(&cnt[ei[EE + e]], 1);
}

__global__ void k_scan(const int* __restrict__ cnt, int* __restrict__ off,
                       int* __restrict__ pos, float* __restrict__ dinv) {
    __shared__ int part[1024];
    int t = threadIdx.x;
    int loc[8];
    int s = 0;
    int base = t * 8;
#pragma unroll
    for (int j = 0; j < 8; ++j) {
        int c = cnt[base + j];
        dinv[base + j] = rsqrtf((float)c + 1.0f);
        loc[j] = s;
        s += c;
    }
    part[t] = s;
    __syncthreads();
    for (int st = 1; st < 1024; st <<= 1) {
        int v = (t >= st) ? part[t - st] : 0;
        __syncthreads();
        part[t] += v;
        __syncthreads();
    }
    int pre = (t > 0) ? part[t - 1] : 0;
#pragma unroll
    for (int j = 0; j < 8; ++j) {
        int val = pre + loc[j];
        off[base + j] = val;
        pos[base + j] = val;
    }
    if (t == 1023) off[NN] = part[1023];
}

__global__ void k_fill(const int* __restrict__ ei, const float* __restrict__ dinv,
                       int* __restrict__ pos, int* __restrict__ csr_src,
                       float* __restrict__ csr_w) {
    int e = blockIdx.x * 256 + threadIdx.x;
    if (e >= EE) return;
    int r = ei[e];
    int c = ei[EE + e];
    int p = atomicAdd(&pos[c], 1);
    csr_src[p] = r;
    csr_w[p] = dinv[r] * dinv[c];
}

// ---------------------------------------------------------------------------
// MX-scaled fp8 MFMA GEMM (scales=1.0): C = act(A @ Bt^T + bias).
// 128x128 tile, BK=128, XOR bank-swizzled staging (verified r8-r11).
// ACT: 0 none, 1 relu, 2 tanh.
// OMODE: 10 fp8 out; 3 fp8 out, z==2 -> transposed-per-doc (vt);
//        20 fused fc2+fc3+pool: tanh, dot fc3_w, block-mean -> util[by]
// ---------------------------------------------------------------------------
template <int ACT, int OMODE, int SWZ>
__global__ __launch_bounds__(256) void gemm_mx(
    const unsigned char* __restrict__ A, const unsigned char* __restrict__ Bt,
    const float* __restrict__ bias, void* __restrict__ Cout,
    int K, int lda, int ldbt, int ldc, int mreal,
    long saz, long sbz, long scz, int sbiasz,
    const float* __restrict__ w3, const float* __restrict__ b3) {
    __shared__ unsigned char As[128 * 128];
    __shared__ unsigned char Bs[128 * 128];

    int bx = blockIdx.x, by = blockIdx.y, bz = blockIdx.z;
    if (SWZ) {
        const int nx = gridDim.x, ny = gridDim.y;
        const int band = ny >> 3;
        int b = (bz * ny + by) * nx + bx;
        const int k = b & 7;
        int s = b >> 3;
        bx = s % nx; s /= nx;
        const int yl = s % band; s /= band;
        bz = s;
        by = k * band + yl;
    }
    const int z = bz;
    A += (size_t)z * saz;
    Bt += (size_t)z * sbz;
    if (bias) bias += (size_t)z * sbiasz;

    const int tid = threadIdx.x;
    const int wave = tid >> 6, lane = tid & 63;
    const int m0 = by * 128;
    const int n0 = bx * 128;
    const int wm = (wave & 1) * 64, wn = (wave >> 1) * 64;
    const int lhi = lane >> 4;
    const int llo = lane & 15;
    f32x4 acc[4][4] = {};

    const int srow = lane >> 3;
    const int sseg = (lane & 7) ^ srow;
    const unsigned char* ag = A + (size_t)(m0 + wave * 32 + srow) * lda + sseg * 16;
    const unsigned char* bg = Bt + (size_t)(n0 + wave * 32 + srow) * ldbt + sseg * 16;
    unsigned char* al = As + wave * 4096;
    unsigned char* bl = Bs + wave * 4096;

    const int rx = llo & 7;
    const int s0 = (2 * lhi) ^ rx;
    const int s1 = (2 * lhi + 1) ^ rx;

    for (int k0 = 0; k0 < K; k0 += 128) {
#pragma unroll
        for (int r = 0; r < 4; ++r) {
            __builtin_amdgcn_global_load_lds((gas_ptr)(ag + k0 + (size_t)r * 8 * lda),
                                             (las_ptr)(al + r * 1024), 16, 0, 0);
            __builtin_amdgcn_global_load_lds((gas_ptr)(bg + k0 + (size_t)r * 8 * ldbt),
                                             (las_ptr)(bl + r * 1024), 16, 0, 0);
        }
        __syncthreads();
        i32x8 af[4], bf[4];
#pragma unroll
        for (int i = 0; i < 4; ++i) {
            const unsigned char* ra = As + (wm + i * 16 + llo) * 128;
            const unsigned char* rb = Bs + (wn + i * 16 + llo) * 128;
            i32x4 a_lo = *(const i32x4*)(ra + s0 * 16);
            i32x4 a_hi = *(const i32x4*)(ra + s1 * 16);
            i32x4 b_lo = *(const i32x4*)(rb + s0 * 16);
            i32x4 b_hi = *(const i32x4*)(rb + s1 * 16);
#pragma unroll
            for (int w = 0; w < 4; ++w) {
                af[i][w] = a_lo[w]; af[i][w + 4] = a_hi[w];
                bf[i][w] = b_lo[w]; bf[i][w + 4] = b_hi[w];
            }
        }
#pragma unroll
        for (int i = 0; i < 4; ++i)
#pragma unroll
            for (int j = 0; j < 4; ++j)
                acc[i][j] = __builtin_amdgcn_mfma_scale_f32_16x16x128_f8f6f4(
                    af[i], bf[j], acc[i][j], 0, 0, 0, 127, 0, 127);
        __syncthreads();
    }

    unsigned char* C8 = (unsigned char*)Cout + (size_t)z * scz;
    float partial = 0.f;
#pragma unroll
    for (int j = 0; j < 4; ++j) {
        const int col = n0 + wn + j * 16 + llo;
        if (col < mreal) {
            const float bv = bias ? bias[col] : 0.f;
#pragma unroll
            for (int i = 0; i < 4; ++i) {
                const int row = m0 + wm + i * 16 + lhi * 4;
                const int rloc = wm + i * 16 + lhi * 4;
#pragma unroll
                for (int r = 0; r < 4; ++r) {
                    float v = acc[i][j][r] + bv;
                    if (ACT == 1) v = fmaxf(v, 0.f);
                    if (ACT == 2) v = tanhf(v);
                    if (OMODE == 10) {
                        C8[(size_t)(row + r) * ldc + col] = f2fp8(v);
                    } else if (OMODE == 3) {
                        if (z < 2)
                            C8[(size_t)(row + r) * ldc + col] = f2fp8(v);
                        else
                            C8[(size_t)by * 65536 + (size_t)col * 128 + rloc + r] = f2fp8(v);
                    } else {  // 20: accumulate fc3 dot
                        partial += v * w3[col];
                    }
                }
            }
        }
    }
    if (OMODE == 20) {
        __shared__ float red[256];
        red[tid] = partial;
        __syncthreads();
        for (int k = 128; k > 0; k >>= 1) {
            if (tid < k) red[tid] += red[tid + k];
            __syncthreads();
        }
        if (tid == 0)
            ((float*)Cout)[by] = red[0] * (1.0f / 128.0f) + b3[0];
    }
}

// ---------------------------------------------------------------------------
// Fused cross-doc attention + next-layer feature GEMM.
// Block z: S = scale*Q@K^T, softmax, O = P@V (kept in LDS fp8, XOR-swizzled),
// then xwout rows z*128.. = O @ Wn^T (LAST: tanh(O@fc1+b)).
// ---------------------------------------------------------------------------
template <int LAST>
__global__ __launch_bounds__(256) void attn_fused(
    const unsigned char* __restrict__ q8, const unsigned char* __restrict__ k8,
    const unsigned char* __restrict__ vt8, const unsigned char* __restrict__ wn8,
    const float* __restrict__ wbias, unsigned char* __restrict__ xwout) {
    __shared__ unsigned char As[16384];  // Q staging, then P (fp8, swizzled)
    __shared__ unsigned char Bs[16384];  // K/V/W staging
    __shared__ unsigned char Os[65536];  // O (128x512 fp8, XOR-seg swizzled)
    __shared__ float smax[2][128];
    __shared__ float ssum[2][128];

    const int z = blockIdx.x, kd = z ^ 1;
    const int tid = threadIdx.x;
    const int wave = tid >> 6, lane = tid & 63;
    const int wm = (wave & 1) * 64, wn = (wave >> 1) * 64;
    const int lhi = lane >> 4, llo = lane & 15;
    const int srow = lane >> 3;
    const int sseg = (lane & 7) ^ srow;
    const int rx = llo & 7;
    const int s0 = (2 * lhi) ^ rx, s1 = (2 * lhi + 1) ^ rx;

    unsigned char* al = As + wave * 4096;
    unsigned char* bl = Bs + wave * 4096;

    // ---- phase 1: S = Q @ K^T ----
    f32x4 acc[4][4] = {};
    const unsigned char* qg = q8 + (size_t)z * 65536 + (wave * 32 + srow) * 512 + sseg * 16;
    const unsigned char* kg = k8 + (size_t)kd * 65536 + (wave * 32 + srow) * 512 + sseg * 16;
    for (int k0 = 0; k0 < 512; k0 += 128) {
#pragma unroll
        for (int r = 0; r < 4; ++r) {
            __builtin_amdgcn_global_load_lds((gas_ptr)(qg + k0 + r * 8 * 512),
                                             (las_ptr)(al + r * 1024), 16, 0, 0);
            __builtin_amdgcn_global_load_lds((gas_ptr)(kg + k0 + r * 8 * 512),
                                             (las_ptr)(bl + r * 1024), 16, 0, 0);
        }
        __syncthreads();
        i32x8 af[4], bf[4];
#pragma unroll
        for (int i = 0; i < 4; ++i) {
            const unsigned char* ra = As + (wm + i * 16 + llo) * 128;
            const unsigned char* rb = Bs + (wn + i * 16 + llo) * 128;
            i32x4 a_lo = *(const i32x4*)(ra + s0 * 16);
            i32x4 a_hi = *(const i32x4*)(ra + s1 * 16);
            i32x4 b_lo = *(const i32x4*)(rb + s0 * 16);
            i32x4 b_hi = *(const i32x4*)(rb + s1 * 16);
#pragma unroll
            for (int w = 0; w < 4; ++w) {
                af[i][w] = a_lo[w]; af[i][w + 4] = a_hi[w];
                bf[i][w] = b_lo[w]; bf[i][w + 4] = b_hi[w];
            }
        }
#pragma unroll
        for (int i = 0; i < 4; ++i)
#pragma unroll
            for (int j = 0; j < 4; ++j)
                acc[i][j] = __builtin_amdgcn_mfma_scale_f32_16x16x128_f8f6f4(
                    af[i], bf[j], acc[i][j], 0, 0, 0, 127, 0, 127);
        __syncthreads();
    }
    const float scale = 0.044194173824159216f;  // 1/sqrt(512)
#pragma unroll
    for (int i = 0; i < 4; ++i)
#pragma unroll
        for (int j = 0; j < 4; ++j)
            acc[i][j] *= scale;

    // ---- phase 2: softmax over rows (cols split wn=0 / wn=64) ----
    const int half = wn >> 6;
    float pm[4][4];
#pragma unroll
    for (int i = 0; i < 4; ++i)
#pragma unroll
        for (int r = 0; r < 4; ++r) {
            float m = fmaxf(fmaxf(acc[i][0][r], acc[i][1][r]),
                            fmaxf(acc[i][2][r], acc[i][3][r]));
#pragma unroll
            for (int msk = 1; msk < 16; msk <<= 1) m = fmaxf(m, __shfl_xor(m, msk));
            pm[i][r] = m;
        }
    if (llo == 0) {
#pragma unroll
        for (int i = 0; i < 4; ++i)
#pragma unroll
            for (int r = 0; r < 4; ++r)
                smax[half][wm + i * 16 + lhi * 4 + r] = pm[i][r];
    }
    __syncthreads();
    float ps[4][4];
#pragma unroll
    for (int i = 0; i < 4; ++i)
#pragma unroll
        for (int r = 0; r < 4; ++r) {
            const int row = wm + i * 16 + lhi * 4 + r;
            const float m = fmaxf(smax[0][row], smax[1][row]);
            float s = 0.f;
#pragma unroll
            for (int j = 0; j < 4; ++j) {
                acc[i][j][r] = __expf(acc[i][j][r] - m);
                s += acc[i][j][r];
            }
#pragma unroll
            for (int msk = 1; msk < 16; msk <<= 1) s += __shfl_xor(s, msk);
            ps[i][r] = s;
        }
    if (llo == 0) {
#pragma unroll
        for (int i = 0; i < 4; ++i)
#pragma unroll
            for (int r = 0; r < 4; ++r)
                ssum[half][wm + i * 16 + lhi * 4 + r] = ps[i][r];
    }
    __syncthreads();
    // write P (fp8) into As, XOR-seg swizzled (8 segs per 128B row)
#pragma unroll
    for (int i = 0; i < 4; ++i)
#pragma unroll
        for (int r = 0; r < 4; ++r) {
            const int row = wm + i * 16 + lhi * 4 + r;
            const float inv = 1.f / (ssum[0][row] + ssum[1][row]);
#pragma unroll
            for (int j = 0; j < 4; ++j) {
                const int seg = (wn >> 4) + j;
                As[row * 128 + (((seg ^ (row & 7))) << 4) + llo] =
                    f2fp8(acc[i][j][r] * inv);
            }
        }
    __syncthreads();

    // ---- phase 3: O = P @ V -> Os (LDS fp8, XOR-seg swizzled, 32 segs/row) ----
    i32x8 pf[4];
#pragma unroll
    for (int i = 0; i < 4; ++i) {
        const unsigned char* ra = As + (wm + i * 16 + llo) * 128;
        i32x4 a_lo = *(const i32x4*)(ra + s0 * 16);
        i32x4 a_hi = *(const i32x4*)(ra + s1 * 16);
#pragma unroll
        for (int w = 0; w < 4; ++w) { pf[i][w] = a_lo[w]; pf[i][w + 4] = a_hi[w]; }
    }
    const unsigned char* vg = vt8 + (size_t)kd * 65536;
    for (int t = 0; t < 4; ++t) {
#pragma unroll
        for (int r = 0; r < 4; ++r)
            __builtin_amdgcn_global_load_lds(
                (gas_ptr)(vg + (t * 128 + wave * 32 + srow + r * 8) * 128 + sseg * 16),
                (las_ptr)(bl + r * 1024), 16, 0, 0);
        __syncthreads();
        i32x8 bf[4];
#pragma unroll
        for (int i = 0; i < 4; ++i) {
            const unsigned char* rb = Bs + (wn + i * 16 + llo) * 128;
            i32x4 b_lo = *(const i32x4*)(rb + s0 * 16);
            i32x4 b_hi = *(const i32x4*)(rb + s1 * 16);
#pragma unroll
            for (int w = 0; w < 4; ++w) { bf[i][w] = b_lo[w]; bf[i][w + 4] = b_hi[w]; }
        }
        f32x4 o[4][4] = {};
#pragma unroll
        for (int i = 0; i < 4; ++i)
#pragma unroll
            for (int j = 0; j < 4; ++j)
                o[i][j] = __builtin_amdgcn_mfma_scale_f32_16x16x128_f8f6f4(
                    pf[i], bf[j], o[i][j], 0, 0, 0, 127, 0, 127);
#pragma unroll
        for (int j = 0; j < 4; ++j) {
            const int seg = t * 8 + (wn >> 4) + j;
#pragma unroll
            for (int i = 0; i < 4; ++i) {
#pragma unroll
                for (int r = 0; r < 4; ++r) {
                    const int row = wm + i * 16 + lhi * 4 + r;
                    Os[row * 512 + ((seg ^ (row & 7)) << 4) + llo] = f2fp8(o[i][j][r]);
                }
            }
        }
        __syncthreads();
    }

    // ---- phase 4: xwout rows = O @ Wn^T (LAST: tanh(+bias)) ----
    for (int xt = 0; xt < 4; ++xt) {
        f32x4 e[4][4] = {};
        for (int k0 = 0; k0 < 512; k0 += 128) {
#pragma unroll
            for (int r = 0; r < 4; ++r)
                __builtin_amdgcn_global_load_lds(
                    (gas_ptr)(wn8 + (size_t)(xt * 128 + wave * 32 + srow + r * 8) * 512 +
                              k0 + sseg * 16),
                    (las_ptr)(bl + r * 1024), 16, 0, 0);
            __syncthreads();
            const int kb = k0 >> 4;  // base seg (multiple of 8)
            i32x8 af[4], bf[4];
#pragma unroll
            for (int i = 0; i < 4; ++i) {
                const unsigned char* ra = Os + (wm + i * 16 + llo) * 512;
                i32x4 a_lo = *(const i32x4*)(ra + (kb + s0) * 16);
                i32x4 a_hi = *(const i32x4*)(ra + (kb + s1) * 16);
                const unsigned char* rb = Bs + (wn + i * 16 + llo) * 128;
                i32x4 b_lo = *(const i32x4*)(rb + s0 * 16);
                i32x4 b_hi = *(const i32x4*)(rb + s1 * 16);
#pragma unroll
                for (int w = 0; w < 4; ++w) {
                    af[i][w] = a_lo[w]; af[i][w + 4] = a_hi[w];
                    bf[i][w] = b_lo[w]; bf[i][w + 4] = b_hi[w];
                }
            }
#pragma unroll
            for (int i = 0; i < 4; ++i)
#pragma unroll
                for (int j = 0; j < 4; ++j)
                    e[i][j] = __builtin_amdgcn_mfma_scale_f32_16x16x128_f8f6f4(
                        af[i], bf[j], e[i][j], 0, 0, 0, 127, 0, 127);
            __syncthreads();
        }
#pragma unroll
        for (int j = 0; j < 4; ++j) {
            const int col = xt * 128 + wn + j * 16 + llo;
            const float bv = LAST ? wbias[col] : 0.f;
#pragma unroll
            for (int i = 0; i < 4; ++i) {
                const size_t row = (size_t)z * 128 + wm + i * 16 + lhi * 4;
#pragma unroll
                for (int r = 0; r < 4; ++r) {
                    float v = e[i][j][r];
                    if (LAST) v = tanhf(v + bv);
                    xwout[(row + r) * 512 + col] = f2fp8(v);
                }
            }
        }
    }
}

// ---------------------------------------------------------------------------
// GCN aggregation (fp8 in/out), 4-edge unroll
// ---------------------------------------------------------------------------
__global__ __launch_bounds__(256) void gcn_agg(const unsigned char* __restrict__ xw8,
                                               const float* __restrict__ bias,
                                               const int* __restrict__ off,
                                               const int* __restrict__ src,
                                               const float* __restrict__ wgt,
                                               const float* __restrict__ dinv,
                                               unsigned char* __restrict__ out) {
    const int node = blockIdx.x;
    const int t = threadIdx.x;
    const int d0 = 2 * t;
    const int beg = off[node], end = off[node + 1];
    float a0 = 0.f, a1 = 0.f;
    int e = beg;
    for (; e + 3 < end; e += 4) {
        const int s0 = src[e], s1 = src[e + 1], s2 = src[e + 2], s3 = src[e + 3];
        const float w0 = wgt[e], w1 = wgt[e + 1], w2 = wgt[e + 2], w3 = wgt[e + 3];
        const unsigned u0 = *(const unsigned short*)(xw8 + (size_t)s0 * DD + d0);
        const unsigned u1 = *(const unsigned short*)(xw8 + (size_t)s1 * DD + d0);
        const unsigned u2 = *(const unsigned short*)(xw8 + (size_t)s2 * DD + d0);
        const unsigned u3 = *(const unsigned short*)(xw8 + (size_t)s3 * DD + d0);
        auto f0 = __builtin_amdgcn_cvt_pk_f32_fp8(u0, false);
        auto f1 = __builtin_amdgcn_cvt_pk_f32_fp8(u1, false);
        auto f2 = __builtin_amdgcn_cvt_pk_f32_fp8(u2, false);
        auto f3 = __builtin_amdgcn_cvt_pk_f32_fp8(u3, false);
        a0 += w0 * f0[0] + w1 * f1[0] + w2 * f2[0] + w3 * f3[0];
        a1 += w0 * f0[1] + w1 * f1[1] + w2 * f2[1] + w3 * f3[1];
    }
    for (; e < end; ++e) {
        const int s0 = src[e];
        const float w0 = wgt[e];
        const unsigned u0 = *(const unsigned short*)(xw8 + (size_t)s0 * DD + d0);
        auto f0 = __builtin_amdgcn_cvt_pk_f32_fp8(u0, false);
        a0 += w0 * f0[0];
        a1 += w0 * f0[1];
    }
    const float ns = dinv[node] * dinv[node];
    const unsigned un = *(const unsigned short*)(xw8 + (size_t)node * DD + d0);
    auto fn = __builtin_amdgcn_cvt_pk_f32_fp8(un, false);
    const float r0 = tanhf(a0 + ns * fn[0] + bias[d0]);
    const float r1 = tanhf(a1 + ns * fn[1] + bias[d0 + 1]);
    unsigned p = (unsigned)__builtin_amdgcn_cvt_pk_fp8_f32(r0, r1, 0, false);
    *(unsigned short*)(out + (size_t)node * DD + d0) = (unsigned short)(p & 0xffff);
}

__global__ void final_out(const float* __restrict__ util, const int* __restrict__ ia,
                          const int* __restrict__ ib, float* __restrict__ out) {
    int i = threadIdx.x;
    if (i < NPAIR) {
        float z = util[ib[i]] - util[ia[i]];
        out[i] = 1.f / (1.f + expf(-z));
    }
}

// ---------------------------------------------------------------------------
extern "C" void kernel_launch(void* const* d_in, const int* in_sizes, int n_in,
                              void* d_out, int out_size, void* d_ws, size_t ws_size,
                              hipStream_t stream) {
    const float* x = (const float*)d_in[0];
    const float* w_in = (const float*)d_in[1];
    const float* b_in = (const float*)d_in[2];
    const float* w_mid = (const float*)d_in[3];
    const float* b_mid = (const float*)d_in[4];
    const float* w_out = (const float*)d_in[5];
    const float* b_out = (const float*)d_in[6];
    const float* fc1_w = (const float*)d_in[7];
    const float* fc1_b = (const float*)d_in[8];
    const float* fc2_w = (const float*)d_in[9];
    const float* fc2_b = (const float*)d_in[10];
    const float* fc3_w = (const float*)d_in[11];
    const float* fc3_b = (const float*)d_in[12];
    const float* qkv1_w = (const float*)d_in[13];
    const float* qkv1_b = (const float*)d_in[14];
    const float* qkv2_w = (const float*)d_in[15];
    const float* qkv2_b = (const float*)d_in[16];
    const float* qkv3_w = (const float*)d_in[17];
    const float* qkv3_b = (const float*)d_in[18];
    const int* ei = (const int*)d_in[19];
    const int* idx_a = (const int*)d_in[22];
    const int* idx_b = (const int*)d_in[23];
    float* out = (float*)d_out;

    char* ws = (char*)d_ws;
    const size_t MB = 1024 * 1024;
    const size_t KB = 1024;
    float* dinv = (float*)(ws + 0);
    int* cnt = (int*)(ws + 64 * KB);
    int* off = (int*)(ws + 128 * KB);
    int* pos = (int*)(ws + 192 * KB);
    int* csrc = (int*)(ws + 256 * KB);
    float* cw = (float*)(ws + 768 * KB);
    float* util = (float*)(ws + 1280 * KB);
    unsigned char* x8 = (unsigned char*)(ws + 2 * MB);       // 1MB fp8
    unsigned char* wt_in8 = (unsigned char*)(ws + 4 * MB);                 // 64KB
    unsigned char* wt_mid8 = (unsigned char*)(ws + 4 * MB + 64 * KB);      // 256KB
    unsigned char* wt_out8 = (unsigned char*)(ws + 4 * MB + 320 * KB);     // 256KB
    unsigned char* wt_fc18 = (unsigned char*)(ws + 4 * MB + 576 * KB);     // 256KB
    unsigned char* wt_fc2p8 = (unsigned char*)(ws + 4 * MB + 832 * KB);    // 64KB padded
    unsigned char* qkv1_8 = (unsigned char*)(ws + 6 * MB);   // 1.5MB
    unsigned char* qkv2_8 = (unsigned char*)(ws + 8 * MB);   // 3MB
    unsigned char* qkv3_8 = (unsigned char*)(ws + 11 * MB);  // 1.5MB
    unsigned char* t1_8 = (unsigned char*)(ws + 25 * MB);    // 24MB
    unsigned char* t2_8 = (unsigned char*)(ws + 49 * MB);    // 24MB
    unsigned char* xw8 = (unsigned char*)(ws + 73 * MB);     // 4MB
    unsigned char* g8 = (unsigned char*)(ws + 77 * MB);      // 4MB
    unsigned char* q8 = (unsigned char*)(ws + 81 * MB);      // 4MB
    unsigned char* k8 = (unsigned char*)(ws + 85 * MB);      // 4MB (q8+4MB)
    unsigned char* vt8 = (unsigned char*)(ws + 89 * MB);     // 4MB (q8+8MB)
    unsigned char* x2_8 = (unsigned char*)(ws + 93 * MB);    // 4MB (ends 97MB)

    // --- fused prep (cast + cnt zero + all weight transposes) ---
    k_prep<<<8096, 256, 0, stream>>>(x, x8, cnt, w_in, wt_in8, w_mid, wt_mid8,
                                     w_out, wt_out8, fc1_w, wt_fc18, fc2_w, wt_fc2p8,
                                     qkv1_w, qkv1_8, qkv2_w, qkv2_8, qkv3_w, qkv3_8);

    // --- degree + CSR build ---
    k_count<<<EE / 256, 256, 0, stream>>>(ei, cnt);
    k_scan<<<1, 1024, 0, stream>>>(cnt, off, pos, dinv);
    k_fill<<<EE / 256, 256, 0, stream>>>(ei, dinv, pos, csrc, cw);

    // layer 1's GCN feature GEMM (x8 @ w_in); later layers get theirs from
    // the previous attn_fused epilogue.
    gemm_mx<0, 10, 1><<<dim3(4, 64), 256, 0, stream>>>(
        x8, wt_in8, nullptr, xw8, F_IN, F_IN, F_IN, 512, 512, 0, 0, 0, 0,
        nullptr, nullptr);

    auto qkv = [&](const float* b) {
        gcn_agg<<<NN, 256, 0, stream>>>(xw8, b, off, csrc, cw, dinv, g8);
        gemm_mx<1, 10, 1><<<dim3(24, 64), 256, 0, stream>>>(
            g8, qkv1_8, qkv1_b, t1_8, 512, 512, 512, 3072, 3072, 0, 0, 0, 0,
            nullptr, nullptr);
        gemm_mx<1, 10, 1><<<dim3(8, 64, 3), 256, 0, stream>>>(
            t1_8, qkv2_8, qkv2_b, t2_8, 1024, 3072, 1024, 3072, 1024,
            1024, 1048576, 1024, 1024, nullptr, nullptr);
        gemm_mx<1, 3, 1><<<dim3(4, 64, 3), 256, 0, stream>>>(
            t2_8, qkv3_8, qkv3_b, q8, 1024, 3072, 1024, 512, 512,
            1024, 524288, 4194304, 512, nullptr, nullptr);
    };

    // L1..L3: attn epilogue computes next layer's xw8 (no act)
    qkv(b_in);
    attn_fused<0><<<NDOC, 256, 0, stream>>>(q8, k8, vt8, wt_mid8, nullptr, xw8);
    qkv(b_mid);
    attn_fused<0><<<NDOC, 256, 0, stream>>>(q8, k8, vt8, wt_mid8, nullptr, xw8);
    qkv(b_mid);
    attn_fused<0><<<NDOC, 256, 0, stream>>>(q8, k8, vt8, wt_out8, nullptr, xw8);
    // L4: attn epilogue computes tanh(O @ fc1 + b) -> x2_8
    qkv(b_out);
    attn_fused<1><<<NDOC, 256, 0, stream>>>(q8, k8, vt8, wt_fc18, fc1_b, x2_8);

    // fc2 + fc3 + pool fused -> util; then pairwise sigmoid
    gemm_mx<2, 20, 0><<<dim3(1, 64), 256, 0, stream>>>(
        x2_8, wt_fc2p8, fc2_b, util, 512, 512, 512, 32, 32, 0, 0, 0, 0,
        fc3_w, fc3_b);
    final_out<<<1, 64, 0, stream>>>(util, idx_a, idx_b, out);
}

// Round 13
// 627.140 us; speedup vs baseline: 1.0888x; 1.0888x over previous
//
#include <hip/hip_runtime.h>
#include <math.h>

#define NN 8192
#define NPD 128
#define F_IN 128
#define DD 512
#define HH 1024
#define EE 131072
#define NDOC 64
#define NPAIR 32

typedef __attribute__((ext_vector_type(4))) float f32x4;
typedef __attribute__((ext_vector_type(4))) int i32x4;
typedef __attribute__((ext_vector_type(8))) int i32x8;
typedef const __attribute__((address_space(1))) void* gas_ptr;
typedef __attribute__((address_space(3))) void* las_ptr;

__device__ __forceinline__ unsigned char f2fp8(float f) {
    return (unsigned char)(__builtin_amdgcn_cvt_pk_fp8_f32(f, f, 0, false) & 0xff);
}

// ---------------------------------------------------------------------------
// Fused prep: x cast to fp8 (1024 blocks) + cnt zero (32) + all weight
// transposes K x M fp32 -> M x K fp8 (job table). fc2 pads M 32->128 zeros.
// ---------------------------------------------------------------------------
__global__ __launch_bounds__(256) void k_prep(
    const float* __restrict__ x, unsigned char* __restrict__ x8,
    int* __restrict__ cnt,
    const float* __restrict__ w_in, unsigned char* __restrict__ wt_in8,
    const float* __restrict__ w_mid, unsigned char* __restrict__ wt_mid8,
    const float* __restrict__ w_out, unsigned char* __restrict__ wt_out8,
    const float* __restrict__ fc1_w, unsigned char* __restrict__ wt_fc18,
    const float* __restrict__ fc2_w, unsigned char* __restrict__ wt_fc2p8,
    const float* __restrict__ qkv1_w, unsigned char* __restrict__ qkv1_8,
    const float* __restrict__ qkv2_w, unsigned char* __restrict__ qkv2_8,
    const float* __restrict__ qkv3_w, unsigned char* __restrict__ qkv3_8) {
    int b = blockIdx.x;
    const int tid = threadIdx.x;
    if (b < 1024) {  // cast x -> fp8
        int i = (b * 256 + tid) * 4;
        float4 v = *(const float4*)(x + i);
        unsigned lo = (unsigned)__builtin_amdgcn_cvt_pk_fp8_f32(v.x, v.y, 0, false) & 0xffffu;
        unsigned hi = (unsigned)__builtin_amdgcn_cvt_pk_fp8_f32(v.z, v.w, 0, false) & 0xffffu;
        *(unsigned*)(x8 + i) = lo | (hi << 16);
        return;
    }
    b -= 1024;
    if (b < 32) { cnt[b * 256 + tid] = 0; return; }
    b -= 32;
    const float* src; unsigned char* dst;
    int K, M, nx, ny, mreal; long sw = 0;
    if (b < 64)        {          src = w_in;   dst = wt_in8;   K = 128;  M = 512;  nx = 16; ny = 4;  mreal = 512; }
    else if (b < 320)  { b -= 64;   src = w_mid;  dst = wt_mid8;  K = 512;  M = 512;  nx = 16; ny = 16; mreal = 512; }
    else if (b < 576)  { b -= 320;  src = w_out;  dst = wt_out8;  K = 512;  M = 512;  nx = 16; ny = 16; mreal = 512; }
    else if (b < 832)  { b -= 576;  src = fc1_w;  dst = wt_fc18;  K = 512;  M = 512;  nx = 16; ny = 16; mreal = 512; }
    else if (b < 896)  { b -= 832;  src = fc2_w;  dst = wt_fc2p8; K = 512;  M = 32;   nx = 4;  ny = 16; mreal = 32; }
    else if (b < 2432) { b -= 896;  src = qkv1_w; dst = qkv1_8;   K = 512;  M = 1024; nx = 32; ny = 16; mreal = 1024; sw = 524288; }
    else if (b < 5504) { b -= 2432; src = qkv2_w; dst = qkv2_8;   K = 1024; M = 1024; nx = 32; ny = 32; mreal = 1024; sw = 1048576; }
    else               { b -= 5504; src = qkv3_w; dst = qkv3_8;   K = 1024; M = 512;  nx = 16; ny = 32; mreal = 512;  sw = 524288; }
    const int bx = (b % nx) * 32;
    const int rest = b / nx;
    const int by = (rest % ny) * 32;
    const int z = rest / ny;
    src += (size_t)z * sw;
    dst += (size_t)z * sw;
    __shared__ float t[32][33];
    const int tx = tid & 31, ty = tid >> 5;
    for (int i = ty; i < 32; i += 8)
        t[i][tx] = (bx + tx < mreal) ? src[(size_t)(by + i) * M + bx + tx] : 0.f;
    __syncthreads();
    for (int i = ty; i < 32; i += 8)
        dst[(size_t)(bx + i) * K + by + tx] = f2fp8(t[tx][i]);
}

// ---------------------------------------------------------------------------
// Degree / CSR construction
// ---------------------------------------------------------------------------
__global__ void k_count(const int* __restrict__ ei, int* __restrict__ cnt) {
    int e = blockIdx.x * 256 + threadIdx.x;
    if (e < EE) atomicAdd(&cnt[ei[EE + e]], 1);
}

__global__ void k_scan(const int* __restrict__ cnt, int* __restrict__ off,
                       int* __restrict__ pos, float* __restrict__ dinv) {
    __shared__ int part[1024];
    int t = threadIdx.x;
    int loc[8];
    int s = 0;
    int base = t * 8;
#pragma unroll
    for (int j = 0; j < 8; ++j) {
        int c = cnt[base + j];
        dinv[base + j] = rsqrtf((float)c + 1.0f);
        loc[j] = s;
        s += c;
    }
    part[t] = s;
    __syncthreads();
    for (int st = 1; st < 1024; st <<= 1) {
        int v = (t >= st) ? part[t - st] : 0;
        __syncthreads();
        part[t] += v;
        __syncthreads();
    }
    int pre = (t > 0) ? part[t - 1] : 0;
#pragma unroll
    for (int j = 0; j < 8; ++j) {
        int val = pre + loc[j];
        off[base + j] = val;
        pos[base + j] = val;
    }
    if (t == 1023) off[NN] = part[1023];
}

__global__ void k_fill(const int* __restrict__ ei, const float* __restrict__ dinv,
                       int* __restrict__ pos, int* __restrict__ csr_src,
                       float* __restrict__ csr_w) {
    int e = blockIdx.x * 256 + threadIdx.x;
    if (e >= EE) return;
    int r = ei[e];
    int c = ei[EE + e];
    int p = atomicAdd(&pos[c], 1);
    csr_src[p] = r;
    csr_w[p] = dinv[r] * dinv[c];
}

// ---------------------------------------------------------------------------
// MX-scaled fp8 MFMA GEMM (scales=1.0): C = act(A @ Bt^T + bias).
// 128x128 tile, BK=128, XOR bank-swizzled staging (verified r8-r11).
// ACT: 0 none, 1 relu, 2 tanh.
// OMODE: 10 fp8 out; 3 fp8 out, z==2 -> transposed-per-doc (vt);
//        20 fused fc2+fc3+pool: tanh, dot fc3_w, block-mean -> util[by]
// ---------------------------------------------------------------------------
template <int ACT, int OMODE, int SWZ>
__global__ __launch_bounds__(256) void gemm_mx(
    const unsigned char* __restrict__ A, const unsigned char* __restrict__ Bt,
    const float* __restrict__ bias, void* __restrict__ Cout,
    int K, int lda, int ldbt, int ldc, int mreal,
    long saz, long sbz, long scz, int sbiasz,
    const float* __restrict__ w3, const float* __restrict__ b3) {
    __shared__ unsigned char As[128 * 128];
    __shared__ unsigned char Bs[128 * 128];

    int bx = blockIdx.x, by = blockIdx.y, bz = blockIdx.z;
    if (SWZ) {
        const int nx = gridDim.x, ny = gridDim.y;
        const int band = ny >> 3;
        int b = (bz * ny + by) * nx + bx;
        const int k = b & 7;
        int s = b >> 3;
        bx = s % nx; s /= nx;
        const int yl = s % band; s /= band;
        bz = s;
        by = k * band + yl;
    }
    const int z = bz;
    A += (size_t)z * saz;
    Bt += (size_t)z * sbz;
    if (bias) bias += (size_t)z * sbiasz;

    const int tid = threadIdx.x;
    const int wave = tid >> 6, lane = tid & 63;
    const int m0 = by * 128;
    const int n0 = bx * 128;
    const int wm = (wave & 1) * 64, wn = (wave >> 1) * 64;
    const int lhi = lane >> 4;
    const int llo = lane & 15;
    f32x4 acc[4][4] = {};

    const int srow = lane >> 3;
    const int sseg = (lane & 7) ^ srow;
    const unsigned char* ag = A + (size_t)(m0 + wave * 32 + srow) * lda + sseg * 16;
    const unsigned char* bg = Bt + (size_t)(n0 + wave * 32 + srow) * ldbt + sseg * 16;
    unsigned char* al = As + wave * 4096;
    unsigned char* bl = Bs + wave * 4096;

    const int rx = llo & 7;
    const int s0 = (2 * lhi) ^ rx;
    const int s1 = (2 * lhi + 1) ^ rx;

    for (int k0 = 0; k0 < K; k0 += 128) {
#pragma unroll
        for (int r = 0; r < 4; ++r) {
            __builtin_amdgcn_global_load_lds((gas_ptr)(ag + k0 + (size_t)r * 8 * lda),
                                             (las_ptr)(al + r * 1024), 16, 0, 0);
            __builtin_amdgcn_global_load_lds((gas_ptr)(bg + k0 + (size_t)r * 8 * ldbt),
                                             (las_ptr)(bl + r * 1024), 16, 0, 0);
        }
        __syncthreads();
        i32x8 af[4], bf[4];
#pragma unroll
        for (int i = 0; i < 4; ++i) {
            const unsigned char* ra = As + (wm + i * 16 + llo) * 128;
            const unsigned char* rb = Bs + (wn + i * 16 + llo) * 128;
            i32x4 a_lo = *(const i32x4*)(ra + s0 * 16);
            i32x4 a_hi = *(const i32x4*)(ra + s1 * 16);
            i32x4 b_lo = *(const i32x4*)(rb + s0 * 16);
            i32x4 b_hi = *(const i32x4*)(rb + s1 * 16);
#pragma unroll
            for (int w = 0; w < 4; ++w) {
                af[i][w] = a_lo[w]; af[i][w + 4] = a_hi[w];
                bf[i][w] = b_lo[w]; bf[i][w + 4] = b_hi[w];
            }
        }
#pragma unroll
        for (int i = 0; i < 4; ++i)
#pragma unroll
            for (int j = 0; j < 4; ++j)
                acc[i][j] = __builtin_amdgcn_mfma_scale_f32_16x16x128_f8f6f4(
                    af[i], bf[j], acc[i][j], 0, 0, 0, 127, 0, 127);
        __syncthreads();
    }

    unsigned char* C8 = (unsigned char*)Cout + (size_t)z * scz;
    float partial = 0.f;
#pragma unroll
    for (int j = 0; j < 4; ++j) {
        const int col = n0 + wn + j * 16 + llo;
        if (col < mreal) {
            const float bv = bias ? bias[col] : 0.f;
#pragma unroll
            for (int i = 0; i < 4; ++i) {
                const int row = m0 + wm + i * 16 + lhi * 4;
                const int rloc = wm + i * 16 + lhi * 4;
#pragma unroll
                for (int r = 0; r < 4; ++r) {
                    float v = acc[i][j][r] + bv;
                    if (ACT == 1) v = fmaxf(v, 0.f);
                    if (ACT == 2) v = tanhf(v);
                    if (OMODE == 10) {
                        C8[(size_t)(row + r) * ldc + col] = f2fp8(v);
                    } else if (OMODE == 3) {
                        if (z < 2)
                            C8[(size_t)(row + r) * ldc + col] = f2fp8(v);
                        else
                            C8[(size_t)by * 65536 + (size_t)col * 128 + rloc + r] = f2fp8(v);
                    } else {  // 20: accumulate fc3 dot
                        partial += v * w3[col];
                    }
                }
            }
        }
    }
    if (OMODE == 20) {
        __shared__ float red[256];
        red[tid] = partial;
        __syncthreads();
        for (int k = 128; k > 0; k >>= 1) {
            if (tid < k) red[tid] += red[tid + k];
            __syncthreads();
        }
        if (tid == 0)
            ((float*)Cout)[by] = red[0] * (1.0f / 128.0f) + b3[0];
    }
}

// ---------------------------------------------------------------------------
// Fused cross-doc attention, 2 blocks per attention-block z (64 q-rows each):
// block b: z = b>>1, qh = b&1. S = scale*Q(64x512)@K^T(128x512), softmax
// (rows fully local to the block), P (64x128 fp8 in LDS, XOR-seg swizzled),
// O = P@V (64x512) -> hout fp8. Grid 2*NDOC = 128, LDS ~26KB.
// ---------------------------------------------------------------------------
__global__ __launch_bounds__(256) void attn_fused(
    const unsigned char* __restrict__ q8, const unsigned char* __restrict__ k8,
    const unsigned char* __restrict__ vt8, unsigned char* __restrict__ hout) {
    __shared__ unsigned char As[8192];   // Q staging (64x128B), then P
    __shared__ unsigned char Bs[16384];  // K / V tiles (128x128B)
    __shared__ float smax[2][64];
    __shared__ float ssum[2][64];

    const int z = blockIdx.x >> 1, qh = blockIdx.x & 1, kd = z ^ 1;
    const int tid = threadIdx.x;
    const int wave = tid >> 6, lane = tid & 63;
    const int wm = (wave & 1) * 32;      // row offset in 64
    const int wn = (wave >> 1) * 64;     // col offset in 128
    const int lhi = lane >> 4, llo = lane & 15;
    const int srow = lane >> 3;
    const int sseg = (lane & 7) ^ srow;
    const int rx = llo & 7;
    const int s0 = (2 * lhi) ^ rx, s1 = (2 * lhi + 1) ^ rx;

    unsigned char* qls = As + wave * 2048;  // wave's 16 Q rows
    unsigned char* kls = Bs + wave * 4096;  // wave's 32 K/V rows

    // ---- phase 1: S = Q @ K^T (64x128) ----
    f32x4 acc[2][4] = {};
    const unsigned char* qg = q8 + (size_t)z * 65536 +
                              (qh * 64 + wave * 16 + srow) * 512 + sseg * 16;
    const unsigned char* kg = k8 + (size_t)kd * 65536 +
                              (wave * 32 + srow) * 512 + sseg * 16;
    for (int k0 = 0; k0 < 512; k0 += 128) {
#pragma unroll
        for (int r = 0; r < 2; ++r)
            __builtin_amdgcn_global_load_lds((gas_ptr)(qg + k0 + r * 8 * 512),
                                             (las_ptr)(qls + r * 1024), 16, 0, 0);
#pragma unroll
        for (int r = 0; r < 4; ++r)
            __builtin_amdgcn_global_load_lds((gas_ptr)(kg + k0 + r * 8 * 512),
                                             (las_ptr)(kls + r * 1024), 16, 0, 0);
        __syncthreads();
        i32x8 af[2], bf[4];
#pragma unroll
        for (int i = 0; i < 2; ++i) {
            const unsigned char* ra = As + (wm + i * 16 + llo) * 128;
            i32x4 a_lo = *(const i32x4*)(ra + s0 * 16);
            i32x4 a_hi = *(const i32x4*)(ra + s1 * 16);
#pragma unroll
            for (int w = 0; w < 4; ++w) { af[i][w] = a_lo[w]; af[i][w + 4] = a_hi[w]; }
        }
#pragma unroll
        for (int j = 0; j < 4; ++j) {
            const unsigned char* rb = Bs + (wn + j * 16 + llo) * 128;
            i32x4 b_lo = *(const i32x4*)(rb + s0 * 16);
            i32x4 b_hi = *(const i32x4*)(rb + s1 * 16);
#pragma unroll
            for (int w = 0; w < 4; ++w) { bf[j][w] = b_lo[w]; bf[j][w + 4] = b_hi[w]; }
        }
#pragma unroll
        for (int i = 0; i < 2; ++i)
#pragma unroll
            for (int j = 0; j < 4; ++j)
                acc[i][j] = __builtin_amdgcn_mfma_scale_f32_16x16x128_f8f6f4(
                    af[i], bf[j], acc[i][j], 0, 0, 0, 127, 0, 127);
        __syncthreads();
    }
    const float scale = 0.044194173824159216f;  // 1/sqrt(512)
#pragma unroll
    for (int i = 0; i < 2; ++i)
#pragma unroll
        for (int j = 0; j < 4; ++j)
            acc[i][j] *= scale;

    // ---- phase 2: softmax over rows (col halves wn=0 / wn=64) ----
    const int half = wn >> 6;
    float pm[2][4];
#pragma unroll
    for (int i = 0; i < 2; ++i)
#pragma unroll
        for (int r = 0; r < 4; ++r) {
            float m = fmaxf(fmaxf(acc[i][0][r], acc[i][1][r]),
                            fmaxf(acc[i][2][r], acc[i][3][r]));
#pragma unroll
            for (int msk = 1; msk < 16; msk <<= 1) m = fmaxf(m, __shfl_xor(m, msk));
            pm[i][r] = m;
        }
    if (llo == 0) {
#pragma unroll
        for (int i = 0; i < 2; ++i)
#pragma unroll
            for (int r = 0; r < 4; ++r)
                smax[half][wm + i * 16 + lhi * 4 + r] = pm[i][r];
    }
    __syncthreads();
    float ps[2][4];
#pragma unroll
    for (int i = 0; i < 2; ++i)
#pragma unroll
        for (int r = 0; r < 4; ++r) {
            const int row = wm + i * 16 + lhi * 4 + r;
            const float m = fmaxf(smax[0][row], smax[1][row]);
            float s = 0.f;
#pragma unroll
            for (int j = 0; j < 4; ++j) {
                acc[i][j][r] = __expf(acc[i][j][r] - m);
                s += acc[i][j][r];
            }
#pragma unroll
            for (int msk = 1; msk < 16; msk <<= 1) s += __shfl_xor(s, msk);
            ps[i][r] = s;
        }
    if (llo == 0) {
#pragma unroll
        for (int i = 0; i < 2; ++i)
#pragma unroll
            for (int r = 0; r < 4; ++r)
                ssum[half][wm + i * 16 + lhi * 4 + r] = ps[i][r];
    }
    __syncthreads();
    // write P (fp8) into As, XOR-seg swizzled (8 segs per 128B row)
#pragma unroll
    for (int i = 0; i < 2; ++i)
#pragma unroll
        for (int r = 0; r < 4; ++r) {
            const int row = wm + i * 16 + lhi * 4 + r;
            const float inv = 1.f / (ssum[0][row] + ssum[1][row]);
#pragma unroll
            for (int j = 0; j < 4; ++j) {
                const int seg = (wn >> 4) + j;
                As[row * 128 + ((seg ^ (row & 7)) << 4) + llo] =
                    f2fp8(acc[i][j][r] * inv);
            }
        }
    __syncthreads();

    // ---- phase 3: O = P @ V (64x512), 4 column tiles of V ----
    i32x8 pf[2];
#pragma unroll
    for (int i = 0; i < 2; ++i) {
        const unsigned char* ra = As + (wm + i * 16 + llo) * 128;
        i32x4 a_lo = *(const i32x4*)(ra + s0 * 16);
        i32x4 a_hi = *(const i32x4*)(ra + s1 * 16);
#pragma unroll
        for (int w = 0; w < 4; ++w) { pf[i][w] = a_lo[w]; pf[i][w + 4] = a_hi[w]; }
    }
    const unsigned char* vg = vt8 + (size_t)kd * 65536 +
                              (wave * 32 + srow) * 128 + sseg * 16;
    for (int t = 0; t < 4; ++t) {
#pragma unroll
        for (int r = 0; r < 4; ++r)
            __builtin_amdgcn_global_load_lds(
                (gas_ptr)(vg + (size_t)(t * 128 + r * 8) * 128),
                (las_ptr)(kls + r * 1024), 16, 0, 0);
        __syncthreads();
        i32x8 bf[4];
#pragma unroll
        for (int j = 0; j < 4; ++j) {
            const unsigned char* rb = Bs + (wn + j * 16 + llo) * 128;
            i32x4 b_lo = *(const i32x4*)(rb + s0 * 16);
            i32x4 b_hi = *(const i32x4*)(rb + s1 * 16);
#pragma unroll
            for (int w = 0; w < 4; ++w) { bf[j][w] = b_lo[w]; bf[j][w + 4] = b_hi[w]; }
        }
        f32x4 o[2][4] = {};
#pragma unroll
        for (int i = 0; i < 2; ++i)
#pragma unroll
            for (int j = 0; j < 4; ++j)
                o[i][j] = __builtin_amdgcn_mfma_scale_f32_16x16x128_f8f6f4(
                    pf[i], bf[j], o[i][j], 0, 0, 0, 127, 0, 127);
#pragma unroll
        for (int j = 0; j < 4; ++j) {
            const int col = t * 128 + wn + j * 16 + llo;
#pragma unroll
            for (int i = 0; i < 2; ++i) {
                const size_t row = (size_t)z * 128 + qh * 64 + wm + i * 16 + lhi * 4;
#pragma unroll
                for (int r = 0; r < 4; ++r)
                    hout[(row + r) * 512 + col] = f2fp8(o[i][j][r]);
            }
        }
        __syncthreads();
    }
}

// ---------------------------------------------------------------------------
// GCN aggregation (fp8 in/out), 4-edge unroll
// ---------------------------------------------------------------------------
__global__ __launch_bounds__(256) void gcn_agg(const unsigned char* __restrict__ xw8,
                                               const float* __restrict__ bias,
                                               const int* __restrict__ off,
                                               const int* __restrict__ src,
                                               const float* __restrict__ wgt,
                                               const float* __restrict__ dinv,
                                               unsigned char* __restrict__ out) {
    const int node = blockIdx.x;
    const int t = threadIdx.x;
    const int d0 = 2 * t;
    const int beg = off[node], end = off[node + 1];
    float a0 = 0.f, a1 = 0.f;
    int e = beg;
    for (; e + 3 < end; e += 4) {
        const int s0 = src[e], s1 = src[e + 1], s2 = src[e + 2], s3 = src[e + 3];
        const float w0 = wgt[e], w1 = wgt[e + 1], w2 = wgt[e + 2], w3 = wgt[e + 3];
        const unsigned u0 = *(const unsigned short*)(xw8 + (size_t)s0 * DD + d0);
        const unsigned u1 = *(const unsigned short*)(xw8 + (size_t)s1 * DD + d0);
        const unsigned u2 = *(const unsigned short*)(xw8 + (size_t)s2 * DD + d0);
        const unsigned u3 = *(const unsigned short*)(xw8 + (size_t)s3 * DD + d0);
        auto f0 = __builtin_amdgcn_cvt_pk_f32_fp8(u0, false);
        auto f1 = __builtin_amdgcn_cvt_pk_f32_fp8(u1, false);
        auto f2 = __builtin_amdgcn_cvt_pk_f32_fp8(u2, false);
        auto f3 = __builtin_amdgcn_cvt_pk_f32_fp8(u3, false);
        a0 += w0 * f0[0] + w1 * f1[0] + w2 * f2[0] + w3 * f3[0];
        a1 += w0 * f0[1] + w1 * f1[1] + w2 * f2[1] + w3 * f3[1];
    }
    for (; e < end; ++e) {
        const int s0 = src[e];
        const float w0 = wgt[e];
        const unsigned u0 = *(const unsigned short*)(xw8 + (size_t)s0 * DD + d0);
        auto f0 = __builtin_amdgcn_cvt_pk_f32_fp8(u0, false);
        a0 += w0 * f0[0];
        a1 += w0 * f0[1];
    }
    const float ns = dinv[node] * dinv[node];
    const unsigned un = *(const unsigned short*)(xw8 + (size_t)node * DD + d0);
    auto fn = __builtin_amdgcn_cvt_pk_f32_fp8(un, false);
    const float r0 = tanhf(a0 + ns * fn[0] + bias[d0]);
    const float r1 = tanhf(a1 + ns * fn[1] + bias[d0 + 1]);
    unsigned p = (unsigned)__builtin_amdgcn_cvt_pk_fp8_f32(r0, r1, 0, false);
    *(unsigned short*)(out + (size_t)node * DD + d0) = (unsigned short)(p & 0xffff);
}

__global__ void final_out(const float* __restrict__ util, const int* __restrict__ ia,
                          const int* __restrict__ ib, float* __restrict__ out) {
    int i = threadIdx.x;
    if (i < NPAIR) {
        float z = util[ib[i]] - util[ia[i]];
        out[i] = 1.f / (1.f + expf(-z));
    }
}

// ---------------------------------------------------------------------------
extern "C" void kernel_launch(void* const* d_in, const int* in_sizes, int n_in,
                              void* d_out, int out_size, void* d_ws, size_t ws_size,
                              hipStream_t stream) {
    const float* x = (const float*)d_in[0];
    const float* w_in = (const float*)d_in[1];
    const float* b_in = (const float*)d_in[2];
    const float* w_mid = (const float*)d_in[3];
    const float* b_mid = (const float*)d_in[4];
    const float* w_out = (const float*)d_in[5];
    const float* b_out = (const float*)d_in[6];
    const float* fc1_w = (const float*)d_in[7];
    const float* fc1_b = (const float*)d_in[8];
    const float* fc2_w = (const float*)d_in[9];
    const float* fc2_b = (const float*)d_in[10];
    const float* fc3_w = (const float*)d_in[11];
    const float* fc3_b = (const float*)d_in[12];
    const float* qkv1_w = (const float*)d_in[13];
    const float* qkv1_b = (const float*)d_in[14];
    const float* qkv2_w = (const float*)d_in[15];
    const float* qkv2_b = (const float*)d_in[16];
    const float* qkv3_w = (const float*)d_in[17];
    const float* qkv3_b = (const float*)d_in[18];
    const int* ei = (const int*)d_in[19];
    const int* idx_a = (const int*)d_in[22];
    const int* idx_b = (const int*)d_in[23];
    float* out = (float*)d_out;

    char* ws = (char*)d_ws;
    const size_t MB = 1024 * 1024;
    const size_t KB = 1024;
    float* dinv = (float*)(ws + 0);
    int* cnt = (int*)(ws + 64 * KB);
    int* off = (int*)(ws + 128 * KB);
    int* pos = (int*)(ws + 192 * KB);
    int* csrc = (int*)(ws + 256 * KB);
    float* cw = (float*)(ws + 768 * KB);
    float* util = (float*)(ws + 1280 * KB);
    unsigned char* x8 = (unsigned char*)(ws + 2 * MB);       // 1MB fp8
    unsigned char* wt_in8 = (unsigned char*)(ws + 4 * MB);                 // 64KB
    unsigned char* wt_mid8 = (unsigned char*)(ws + 4 * MB + 64 * KB);      // 256KB
    unsigned char* wt_out8 = (unsigned char*)(ws + 4 * MB + 320 * KB);     // 256KB
    unsigned char* wt_fc18 = (unsigned char*)(ws + 4 * MB + 576 * KB);     // 256KB
    unsigned char* wt_fc2p8 = (unsigned char*)(ws + 4 * MB + 832 * KB);    // 64KB padded
    unsigned char* qkv1_8 = (unsigned char*)(ws + 6 * MB);   // 1.5MB
    unsigned char* qkv2_8 = (unsigned char*)(ws + 8 * MB);   // 3MB
    unsigned char* qkv3_8 = (unsigned char*)(ws + 11 * MB);  // 1.5MB
    unsigned char* h8 = (unsigned char*)(ws + 21 * MB);      // 4MB fp8
    unsigned char* t1_8 = (unsigned char*)(ws + 25 * MB);    // 24MB
    unsigned char* t2_8 = (unsigned char*)(ws + 49 * MB);    // 24MB
    unsigned char* xw8 = (unsigned char*)(ws + 73 * MB);     // 4MB
    unsigned char* g8 = (unsigned char*)(ws + 77 * MB);      // 4MB
    unsigned char* q8 = (unsigned char*)(ws + 81 * MB);      // 4MB
    unsigned char* k8 = (unsigned char*)(ws + 85 * MB);      // 4MB (q8+4MB)
    unsigned char* vt8 = (unsigned char*)(ws + 89 * MB);     // 4MB (q8+8MB)
    unsigned char* x2_8 = (unsigned char*)(ws + 93 * MB);    // 4MB (ends 97MB)

    // --- fused prep (cast + cnt zero + all weight transposes) ---
    k_prep<<<8096, 256, 0, stream>>>(x, x8, cnt, w_in, wt_in8, w_mid, wt_mid8,
                                     w_out, wt_out8, fc1_w, wt_fc18, fc2_w, wt_fc2p8,
                                     qkv1_w, qkv1_8, qkv2_w, qkv2_8, qkv3_w, qkv3_8);

    // --- degree + CSR build ---
    k_count<<<EE / 256, 256, 0, stream>>>(ei, cnt);
    k_scan<<<1, 1024, 0, stream>>>(cnt, off, pos, dinv);
    k_fill<<<EE / 256, 256, 0, stream>>>(ei, dinv, pos, csrc, cw);

    auto layer = [&](const unsigned char* hin8, const unsigned char* wt8,
                     const float* b, int Kin) {
        // GCN (MX fp8): xw8 = hin @ w, aggregate -> g8 (fp8)
        gemm_mx<0, 10, 1><<<dim3(4, 64), 256, 0, stream>>>(
            hin8, wt8, nullptr, xw8, Kin, Kin, Kin, 512, 512, 0, 0, 0, 0,
            nullptr, nullptr);
        gcn_agg<<<NN, 256, 0, stream>>>(xw8, b, off, csrc, cw, dinv, g8);
        // qkv MLP (MX fp8): qkv1 wide M=3072, qkv2 z=3, qkv3 z=3 (v transposed)
        gemm_mx<1, 10, 1><<<dim3(24, 64), 256, 0, stream>>>(
            g8, qkv1_8, qkv1_b, t1_8, 512, 512, 512, 3072, 3072, 0, 0, 0, 0,
            nullptr, nullptr);
        gemm_mx<1, 10, 1><<<dim3(8, 64, 3), 256, 0, stream>>>(
            t1_8, qkv2_8, qkv2_b, t2_8, 1024, 3072, 1024, 3072, 1024,
            1024, 1048576, 1024, 1024, nullptr, nullptr);
        gemm_mx<1, 3, 1><<<dim3(4, 64, 3), 256, 0, stream>>>(
            t2_8, qkv3_8, qkv3_b, q8, 1024, 3072, 1024, 512, 512,
            1024, 524288, 4194304, 512, nullptr, nullptr);
        // fused attention (2 blocks per doc-pair block): -> h8 (fp8)
        attn_fused<<<2 * NDOC, 256, 0, stream>>>(q8, k8, vt8, h8);
    };

    layer(x8, wt_in8, b_in, F_IN);
    layer(h8, wt_mid8, b_mid, DD);
    layer(h8, wt_mid8, b_mid, DD);
    layer(h8, wt_out8, b_out, DD);

    // final FCs (MX fp8) + pool + pairwise sigmoid
    gemm_mx<2, 10, 1><<<dim3(4, 64), 256, 0, stream>>>(
        h8, wt_fc18, fc1_b, x2_8, 512, 512, 512, 512, 512, 0, 0, 0, 0,
        nullptr, nullptr);
    gemm_mx<2, 20, 0><<<dim3(1, 64), 256, 0, stream>>>(
        x2_8, wt_fc2p8, fc2_b, util, 512, 512, 512, 32, 32, 0, 0, 0, 0,
        fc3_w, fc3_b);
    final_out<<<1, 64, 0, stream>>>(util, idx_a, idx_b, out);
}

// Round 14
// 617.277 us; speedup vs baseline: 1.1062x; 1.0160x over previous
//
#include <hip/hip_runtime.h>
#include <math.h>

#define NN 8192
#define NPD 128
#define F_IN 128
#define DD 512
#define HH 1024
#define EE 131072
#define NDOC 64
#define NPAIR 32

typedef __attribute__((ext_vector_type(4))) float f32x4;
typedef __attribute__((ext_vector_type(4))) int i32x4;
typedef __attribute__((ext_vector_type(8))) int i32x8;
typedef const __attribute__((address_space(1))) void* gas_ptr;
typedef __attribute__((address_space(3))) void* las_ptr;

__device__ __forceinline__ unsigned char f2fp8(float f) {
    return (unsigned char)(__builtin_amdgcn_cvt_pk_fp8_f32(f, f, 0, false) & 0xff);
}

// ---------------------------------------------------------------------------
// Fused prep: x cast to fp8 (1024 blocks) + cnt zero (32) + all weight
// transposes K x M fp32 -> M x K fp8 (job table). fc2 pads M 32->128 zeros.
// ---------------------------------------------------------------------------
__global__ __launch_bounds__(256) void k_prep(
    const float* __restrict__ x, unsigned char* __restrict__ x8,
    int* __restrict__ cnt,
    const float* __restrict__ w_in, unsigned char* __restrict__ wt_in8,
    const float* __restrict__ w_mid, unsigned char* __restrict__ wt_mid8,
    const float* __restrict__ w_out, unsigned char* __restrict__ wt_out8,
    const float* __restrict__ fc1_w, unsigned char* __restrict__ wt_fc18,
    const float* __restrict__ fc2_w, unsigned char* __restrict__ wt_fc2p8,
    const float* __restrict__ qkv1_w, unsigned char* __restrict__ qkv1_8,
    const float* __restrict__ qkv2_w, unsigned char* __restrict__ qkv2_8,
    const float* __restrict__ qkv3_w, unsigned char* __restrict__ qkv3_8) {
    int b = blockIdx.x;
    const int tid = threadIdx.x;
    if (b < 1024) {  // cast x -> fp8
        int i = (b * 256 + tid) * 4;
        float4 v = *(const float4*)(x + i);
        unsigned lo = (unsigned)__builtin_amdgcn_cvt_pk_fp8_f32(v.x, v.y, 0, false) & 0xffffu;
        unsigned hi = (unsigned)__builtin_amdgcn_cvt_pk_fp8_f32(v.z, v.w, 0, false) & 0xffffu;
        *(unsigned*)(x8 + i) = lo | (hi << 16);
        return;
    }
    b -= 1024;
    if (b < 32) { cnt[b * 256 + tid] = 0; return; }
    b -= 32;
    const float* src; unsigned char* dst;
    int K, M, nx, ny, mreal; long sw = 0;
    if (b < 64)        {          src = w_in;   dst = wt_in8;   K = 128;  M = 512;  nx = 16; ny = 4;  mreal = 512; }
    else if (b < 320)  { b -= 64;   src = w_mid;  dst = wt_mid8;  K = 512;  M = 512;  nx = 16; ny = 16; mreal = 512; }
    else if (b < 576)  { b -= 320;  src = w_out;  dst = wt_out8;  K = 512;  M = 512;  nx = 16; ny = 16; mreal = 512; }
    else if (b < 832)  { b -= 576;  src = fc1_w;  dst = wt_fc18;  K = 512;  M = 512;  nx = 16; ny = 16; mreal = 512; }
    else if (b < 896)  { b -= 832;  src = fc2_w;  dst = wt_fc2p8; K = 512;  M = 32;   nx = 4;  ny = 16; mreal = 32; }
    else if (b < 2432) { b -= 896;  src = qkv1_w; dst = qkv1_8;   K = 512;  M = 1024; nx = 32; ny = 16; mreal = 1024; sw = 524288; }
    else if (b < 5504) { b -= 2432; src = qkv2_w; dst = qkv2_8;   K = 1024; M = 1024; nx = 32; ny = 32; mreal = 1024; sw = 1048576; }
    else               { b -= 5504; src = qkv3_w; dst = qkv3_8;   K = 1024; M = 512;  nx = 16; ny = 32; mreal = 512;  sw = 524288; }
    const int bx = (b % nx) * 32;
    const int rest = b / nx;
    const int by = (rest % ny) * 32;
    const int z = rest / ny;
    src += (size_t)z * sw;
    dst += (size_t)z * sw;
    __shared__ float t[32][33];
    const int tx = tid & 31, ty = tid >> 5;
    for (int i = ty; i < 32; i += 8)
        t[i][tx] = (bx + tx < mreal) ? src[(size_t)(by + i) * M + bx + tx] : 0.f;
    __syncthreads();
    for (int i = ty; i < 32; i += 8)
        dst[(size_t)(bx + i) * K + by + tx] = f2fp8(t[tx][i]);
}

// ---------------------------------------------------------------------------
// Degree / CSR construction
// ---------------------------------------------------------------------------
__global__ void k_count(const int* __restrict__ ei, int* __restrict__ cnt) {
    int e = blockIdx.x * 256 + threadIdx.x;
    if (e < EE) atomicAdd(&cnt[ei[EE + e]], 1);
}

__global__ void k_scan(const int* __restrict__ cnt, int* __restrict__ off,
                       int* __restrict__ pos, float* __restrict__ dinv) {
    __shared__ int part[1024];
    int t = threadIdx.x;
    int loc[8];
    int s = 0;
    int base = t * 8;
#pragma unroll
    for (int j = 0; j < 8; ++j) {
        int c = cnt[base + j];
        dinv[base + j] = rsqrtf((float)c + 1.0f);
        loc[j] = s;
        s += c;
    }
    part[t] = s;
    __syncthreads();
    for (int st = 1; st < 1024; st <<= 1) {
        int v = (t >= st) ? part[t - st] : 0;
        __syncthreads();
        part[t] += v;
        __syncthreads();
    }
    int pre = (t > 0) ? part[t - 1] : 0;
#pragma unroll
    for (int j = 0; j < 8; ++j) {
        int val = pre + loc[j];
        off[base + j] = val;
        pos[base + j] = val;
    }
    if (t == 1023) off[NN] = part[1023];
}

__global__ void k_fill(const int* __restrict__ ei, const float* __restrict__ dinv,
                       int* __restrict__ pos, int* __restrict__ csr_src,
                       float* __restrict__ csr_w) {
    int e = blockIdx.x * 256 + threadIdx.x;
    if (e >= EE) return;
    int r = ei[e];
    int c = ei[EE + e];
    int p = atomicAdd(&pos[c], 1);
    csr_src[p] = r;
    csr_w[p] = dinv[r] * dinv[c];
}

// ---------------------------------------------------------------------------
// MX-scaled fp8 MFMA GEMM (scales=1.0): C = act(A @ Bt^T + bias).
// 128x128 tile, BK=128, XOR bank-swizzled staging (verified r8-r13).
// ACT: 0 none, 1 relu, 2 tanh.
// OMODE: 10 fp8 out; 3 fp8 out, z==2 -> transposed-per-doc (vt);
//        20 fused fc2+fc3+pool: tanh, dot fc3_w, block-mean -> util[by]
// ---------------------------------------------------------------------------
template <int ACT, int OMODE, int SWZ>
__global__ __launch_bounds__(256) void gemm_mx(
    const unsigned char* __restrict__ A, const unsigned char* __restrict__ Bt,
    const float* __restrict__ bias, void* __restrict__ Cout,
    int K, int lda, int ldbt, int ldc, int mreal,
    long saz, long sbz, long scz, int sbiasz,
    const float* __restrict__ w3, const float* __restrict__ b3) {
    __shared__ unsigned char As[128 * 128];
    __shared__ unsigned char Bs[128 * 128];

    int bx = blockIdx.x, by = blockIdx.y, bz = blockIdx.z;
    if (SWZ) {
        const int nx = gridDim.x, ny = gridDim.y;
        const int band = ny >> 3;
        int b = (bz * ny + by) * nx + bx;
        const int k = b & 7;
        int s = b >> 3;
        bx = s % nx; s /= nx;
        const int yl = s % band; s /= band;
        bz = s;
        by = k * band + yl;
    }
    const int z = bz;
    A += (size_t)z * saz;
    Bt += (size_t)z * sbz;
    if (bias) bias += (size_t)z * sbiasz;

    const int tid = threadIdx.x;
    const int wave = tid >> 6, lane = tid & 63;
    const int m0 = by * 128;
    const int n0 = bx * 128;
    const int wm = (wave & 1) * 64, wn = (wave >> 1) * 64;
    const int lhi = lane >> 4;
    const int llo = lane & 15;
    f32x4 acc[4][4] = {};

    const int srow = lane >> 3;
    const int sseg = (lane & 7) ^ srow;
    const unsigned char* ag = A + (size_t)(m0 + wave * 32 + srow) * lda + sseg * 16;
    const unsigned char* bg = Bt + (size_t)(n0 + wave * 32 + srow) * ldbt + sseg * 16;
    unsigned char* al = As + wave * 4096;
    unsigned char* bl = Bs + wave * 4096;

    const int rx = llo & 7;
    const int s0 = (2 * lhi) ^ rx;
    const int s1 = (2 * lhi + 1) ^ rx;

    for (int k0 = 0; k0 < K; k0 += 128) {
#pragma unroll
        for (int r = 0; r < 4; ++r) {
            __builtin_amdgcn_global_load_lds((gas_ptr)(ag + k0 + (size_t)r * 8 * lda),
                                             (las_ptr)(al + r * 1024), 16, 0, 0);
            __builtin_amdgcn_global_load_lds((gas_ptr)(bg + k0 + (size_t)r * 8 * ldbt),
                                             (las_ptr)(bl + r * 1024), 16, 0, 0);
        }
        __syncthreads();
        i32x8 af[4], bf[4];
#pragma unroll
        for (int i = 0; i < 4; ++i) {
            const unsigned char* ra = As + (wm + i * 16 + llo) * 128;
            const unsigned char* rb = Bs + (wn + i * 16 + llo) * 128;
            i32x4 a_lo = *(const i32x4*)(ra + s0 * 16);
            i32x4 a_hi = *(const i32x4*)(ra + s1 * 16);
            i32x4 b_lo = *(const i32x4*)(rb + s0 * 16);
            i32x4 b_hi = *(const i32x4*)(rb + s1 * 16);
#pragma unroll
            for (int w = 0; w < 4; ++w) {
                af[i][w] = a_lo[w]; af[i][w + 4] = a_hi[w];
                bf[i][w] = b_lo[w]; bf[i][w + 4] = b_hi[w];
            }
        }
#pragma unroll
        for (int i = 0; i < 4; ++i)
#pragma unroll
            for (int j = 0; j < 4; ++j)
                acc[i][j] = __builtin_amdgcn_mfma_scale_f32_16x16x128_f8f6f4(
                    af[i], bf[j], acc[i][j], 0, 0, 0, 127, 0, 127);
        __syncthreads();
    }

    unsigned char* C8 = (unsigned char*)Cout + (size_t)z * scz;
    float partial = 0.f;
#pragma unroll
    for (int j = 0; j < 4; ++j) {
        const int col = n0 + wn + j * 16 + llo;
        if (col < mreal) {
            const float bv = bias ? bias[col] : 0.f;
#pragma unroll
            for (int i = 0; i < 4; ++i) {
                const int row = m0 + wm + i * 16 + lhi * 4;
                const int rloc = wm + i * 16 + lhi * 4;
#pragma unroll
                for (int r = 0; r < 4; ++r) {
                    float v = acc[i][j][r] + bv;
                    if (ACT == 1) v = fmaxf(v, 0.f);
                    if (ACT == 2) v = tanhf(v);
                    if (OMODE == 10) {
                        C8[(size_t)(row + r) * ldc + col] = f2fp8(v);
                    } else if (OMODE == 3) {
                        if (z < 2)
                            C8[(size_t)(row + r) * ldc + col] = f2fp8(v);
                        else
                            C8[(size_t)by * 65536 + (size_t)col * 128 + rloc + r] = f2fp8(v);
                    } else {  // 20: accumulate fc3 dot
                        partial += v * w3[col];
                    }
                }
            }
        }
    }
    if (OMODE == 20) {
        __shared__ float red[256];
        red[tid] = partial;
        __syncthreads();
        for (int k = 128; k > 0; k >>= 1) {
            if (tid < k) red[tid] += red[tid + k];
            __syncthreads();
        }
        if (tid == 0)
            ((float*)Cout)[by] = red[0] * (1.0f / 128.0f) + b3[0];
    }
}

// ---------------------------------------------------------------------------
// Fused cross-doc attention, 4 blocks per attention-block z (32 q-rows each):
// block b: z = b>>2, qq = b&3. S = scale*Q(32x512)@K^T(128x512), softmax
// (rows block-local), P (32x128 fp8 LDS, XOR-seg swizzled), O = P@V (32x512)
// -> hout fp8. Grid 4*NDOC = 256 (one block per CU), LDS ~21KB.
// ---------------------------------------------------------------------------
__global__ __launch_bounds__(256) void attn_fused(
    const unsigned char* __restrict__ q8, const unsigned char* __restrict__ k8,
    const unsigned char* __restrict__ vt8, unsigned char* __restrict__ hout) {
    __shared__ unsigned char As[4096];   // Q staging (32x128B), then P
    __shared__ unsigned char Bs[16384];  // K / V tiles (128x128B)
    __shared__ float smax[2][32];
    __shared__ float ssum[2][32];

    const int z = blockIdx.x >> 2, qq = blockIdx.x & 3, kd = z ^ 1;
    const int tid = threadIdx.x;
    const int wave = tid >> 6, lane = tid & 63;
    const int wm = (wave & 1) * 16;      // row offset in 32
    const int wn = (wave >> 1) * 64;     // col offset in 128
    const int lhi = lane >> 4, llo = lane & 15;
    const int srow = lane >> 3;
    const int sseg = (lane & 7) ^ srow;
    const int rx = llo & 7;
    const int s0 = (2 * lhi) ^ rx, s1 = (2 * lhi + 1) ^ rx;

    unsigned char* qls = As + wave * 1024;  // wave's 8 Q rows
    unsigned char* kls = Bs + wave * 4096;  // wave's 32 K/V rows

    // ---- phase 1: S = Q @ K^T (32x128) ----
    f32x4 acc[4] = {};
    const unsigned char* qg = q8 + (size_t)z * 65536 +
                              (qq * 32 + wave * 8 + srow) * 512 + sseg * 16;
    const unsigned char* kg = k8 + (size_t)kd * 65536 +
                              (wave * 32 + srow) * 512 + sseg * 16;
    for (int k0 = 0; k0 < 512; k0 += 128) {
        __builtin_amdgcn_global_load_lds((gas_ptr)(qg + k0), (las_ptr)qls, 16, 0, 0);
#pragma unroll
        for (int r = 0; r < 4; ++r)
            __builtin_amdgcn_global_load_lds((gas_ptr)(kg + k0 + r * 8 * 512),
                                             (las_ptr)(kls + r * 1024), 16, 0, 0);
        __syncthreads();
        i32x8 af, bf[4];
        {
            const unsigned char* ra = As + (wm + llo) * 128;
            i32x4 a_lo = *(const i32x4*)(ra + s0 * 16);
            i32x4 a_hi = *(const i32x4*)(ra + s1 * 16);
#pragma unroll
            for (int w = 0; w < 4; ++w) { af[w] = a_lo[w]; af[w + 4] = a_hi[w]; }
        }
#pragma unroll
        for (int j = 0; j < 4; ++j) {
            const unsigned char* rb = Bs + (wn + j * 16 + llo) * 128;
            i32x4 b_lo = *(const i32x4*)(rb + s0 * 16);
            i32x4 b_hi = *(const i32x4*)(rb + s1 * 16);
#pragma unroll
            for (int w = 0; w < 4; ++w) { bf[j][w] = b_lo[w]; bf[j][w + 4] = b_hi[w]; }
        }
#pragma unroll
        for (int j = 0; j < 4; ++j)
            acc[j] = __builtin_amdgcn_mfma_scale_f32_16x16x128_f8f6f4(
                af, bf[j], acc[j], 0, 0, 0, 127, 0, 127);
        __syncthreads();
    }
    const float scale = 0.044194173824159216f;  // 1/sqrt(512)
#pragma unroll
    for (int j = 0; j < 4; ++j) acc[j] *= scale;

    // ---- phase 2: softmax over rows (col halves wn=0 / wn=64) ----
    const int half = wn >> 6;
    float pm[4];
#pragma unroll
    for (int r = 0; r < 4; ++r) {
        float m = fmaxf(fmaxf(acc[0][r], acc[1][r]), fmaxf(acc[2][r], acc[3][r]));
#pragma unroll
        for (int msk = 1; msk < 16; msk <<= 1) m = fmaxf(m, __shfl_xor(m, msk));
        pm[r] = m;
    }
    if (llo == 0) {
#pragma unroll
        for (int r = 0; r < 4; ++r) smax[half][wm + lhi * 4 + r] = pm[r];
    }
    __syncthreads();
    float ps[4];
#pragma unroll
    for (int r = 0; r < 4; ++r) {
        const int row = wm + lhi * 4 + r;
        const float m = fmaxf(smax[0][row], smax[1][row]);
        float s = 0.f;
#pragma unroll
        for (int j = 0; j < 4; ++j) {
            acc[j][r] = __expf(acc[j][r] - m);
            s += acc[j][r];
        }
#pragma unroll
        for (int msk = 1; msk < 16; msk <<= 1) s += __shfl_xor(s, msk);
        ps[r] = s;
    }
    if (llo == 0) {
#pragma unroll
        for (int r = 0; r < 4; ++r) ssum[half][wm + lhi * 4 + r] = ps[r];
    }
    __syncthreads();
    // write P (fp8) into As, XOR-seg swizzled (8 segs per 128B row)
#pragma unroll
    for (int r = 0; r < 4; ++r) {
        const int row = wm + lhi * 4 + r;
        const float inv = 1.f / (ssum[0][row] + ssum[1][row]);
#pragma unroll
        for (int j = 0; j < 4; ++j) {
            const int seg = (wn >> 4) + j;
            As[row * 128 + ((seg ^ (row & 7)) << 4) + llo] = f2fp8(acc[j][r] * inv);
        }
    }
    __syncthreads();

    // ---- phase 3: O = P @ V (32x512), 4 column tiles of V ----
    i32x8 pf;
    {
        const unsigned char* ra = As + (wm + llo) * 128;
        i32x4 a_lo = *(const i32x4*)(ra + s0 * 16);
        i32x4 a_hi = *(const i32x4*)(ra + s1 * 16);
#pragma unroll
        for (int w = 0; w < 4; ++w) { pf[w] = a_lo[w]; pf[w + 4] = a_hi[w]; }
    }
    const unsigned char* vg = vt8 + (size_t)kd * 65536 +
                              (wave * 32 + srow) * 128 + sseg * 16;
    for (int t = 0; t < 4; ++t) {
#pragma unroll
        for (int r = 0; r < 4; ++r)
            __builtin_amdgcn_global_load_lds(
                (gas_ptr)(vg + (size_t)(t * 128 + r * 8) * 128),
                (las_ptr)(kls + r * 1024), 16, 0, 0);
        __syncthreads();
        i32x8 bf[4];
#pragma unroll
        for (int j = 0; j < 4; ++j) {
            const unsigned char* rb = Bs + (wn + j * 16 + llo) * 128;
            i32x4 b_lo = *(const i32x4*)(rb + s0 * 16);
            i32x4 b_hi = *(const i32x4*)(rb + s1 * 16);
#pragma unroll
            for (int w = 0; w < 4; ++w) { bf[j][w] = b_lo[w]; bf[j][w + 4] = b_hi[w]; }
        }
        f32x4 o[4] = {};
#pragma unroll
        for (int j = 0; j < 4; ++j)
            o[j] = __builtin_amdgcn_mfma_scale_f32_16x16x128_f8f6f4(
                pf, bf[j], o[j], 0, 0, 0, 127, 0, 127);
#pragma unroll
        for (int j = 0; j < 4; ++j) {
            const int col = t * 128 + wn + j * 16 + llo;
            const size_t row = (size_t)z * 128 + qq * 32 + wm + lhi * 4;
#pragma unroll
            for (int r = 0; r < 4; ++r)
                hout[(row + r) * 512 + col] = f2fp8(o[j][r]);
        }
        __syncthreads();
    }
}

// ---------------------------------------------------------------------------
// GCN aggregation BEFORE the feature GEMM (linear commute):
// u[n] = sum_e w_e * h[src_e] + dinv[n]^2 * h[n]   (fp8 in/out, no act)
// one block per node, thread t handles dims 2t,2t+1 (guard d0 < D), 4-edge unroll
// ---------------------------------------------------------------------------
__global__ __launch_bounds__(256) void agg8(const unsigned char* __restrict__ h8,
                                            const int* __restrict__ off,
                                            const int* __restrict__ src,
                                            const float* __restrict__ wgt,
                                            const float* __restrict__ dinv,
                                            unsigned char* __restrict__ u8, int D) {
    const int node = blockIdx.x;
    const int t = threadIdx.x;
    const int d0 = 2 * t;
    if (d0 >= D) return;
    const int beg = off[node], end = off[node + 1];
    float a0 = 0.f, a1 = 0.f;
    int e = beg;
    for (; e + 3 < end; e += 4) {
        const int s0 = src[e], s1 = src[e + 1], s2 = src[e + 2], s3 = src[e + 3];
        const float w0 = wgt[e], w1 = wgt[e + 1], w2 = wgt[e + 2], w3 = wgt[e + 3];
        const unsigned u0 = *(const unsigned short*)(h8 + (size_t)s0 * D + d0);
        const unsigned u1 = *(const unsigned short*)(h8 + (size_t)s1 * D + d0);
        const unsigned u2 = *(const unsigned short*)(h8 + (size_t)s2 * D + d0);
        const unsigned u3 = *(const unsigned short*)(h8 + (size_t)s3 * D + d0);
        auto f0 = __builtin_amdgcn_cvt_pk_f32_fp8(u0, false);
        auto f1 = __builtin_amdgcn_cvt_pk_f32_fp8(u1, false);
        auto f2 = __builtin_amdgcn_cvt_pk_f32_fp8(u2, false);
        auto f3 = __builtin_amdgcn_cvt_pk_f32_fp8(u3, false);
        a0 += w0 * f0[0] + w1 * f1[0] + w2 * f2[0] + w3 * f3[0];
        a1 += w0 * f0[1] + w1 * f1[1] + w2 * f2[1] + w3 * f3[1];
    }
    for (; e < end; ++e) {
        const int s0 = src[e];
        const float w0 = wgt[e];
        const unsigned u0 = *(const unsigned short*)(h8 + (size_t)s0 * D + d0);
        auto f0 = __builtin_amdgcn_cvt_pk_f32_fp8(u0, false);
        a0 += w0 * f0[0];
        a1 += w0 * f0[1];
    }
    const float ns = dinv[node] * dinv[node];
    const unsigned un = *(const unsigned short*)(h8 + (size_t)node * D + d0);
    auto fn = __builtin_amdgcn_cvt_pk_f32_fp8(un, false);
    const float r0 = a0 + ns * fn[0];
    const float r1 = a1 + ns * fn[1];
    unsigned p = (unsigned)__builtin_amdgcn_cvt_pk_fp8_f32(r0, r1, 0, false);
    *(unsigned short*)(u8 + (size_t)node * D + d0) = (unsigned short)(p & 0xffff);
}

__global__ void final_out(const float* __restrict__ util, const int* __restrict__ ia,
                          const int* __restrict__ ib, float* __restrict__ out) {
    int i = threadIdx.x;
    if (i < NPAIR) {
        float z = util[ib[i]] - util[ia[i]];
        out[i] = 1.f / (1.f + expf(-z));
    }
}

// ---------------------------------------------------------------------------
extern "C" void kernel_launch(void* const* d_in, const int* in_sizes, int n_in,
                              void* d_out, int out_size, void* d_ws, size_t ws_size,
                              hipStream_t stream) {
    const float* x = (const float*)d_in[0];
    const float* w_in = (const float*)d_in[1];
    const float* b_in = (const float*)d_in[2];
    const float* w_mid = (const float*)d_in[3];
    const float* b_mid = (const float*)d_in[4];
    const float* w_out = (const float*)d_in[5];
    const float* b_out = (const float*)d_in[6];
    const float* fc1_w = (const float*)d_in[7];
    const float* fc1_b = (const float*)d_in[8];
    const float* fc2_w = (const float*)d_in[9];
    const float* fc2_b = (const float*)d_in[10];
    const float* fc3_w = (const float*)d_in[11];
    const float* fc3_b = (const float*)d_in[12];
    const float* qkv1_w = (const float*)d_in[13];
    const float* qkv1_b = (const float*)d_in[14];
    const float* qkv2_w = (const float*)d_in[15];
    const float* qkv2_b = (const float*)d_in[16];
    const float* qkv3_w = (const float*)d_in[17];
    const float* qkv3_b = (const float*)d_in[18];
    const int* ei = (const int*)d_in[19];
    const int* idx_a = (const int*)d_in[22];
    const int* idx_b = (const int*)d_in[23];
    float* out = (float*)d_out;

    char* ws = (char*)d_ws;
    const size_t MB = 1024 * 1024;
    const size_t KB = 1024;
    float* dinv = (float*)(ws + 0);
    int* cnt = (int*)(ws + 64 * KB);
    int* off = (int*)(ws + 128 * KB);
    int* pos = (int*)(ws + 192 * KB);
    int* csrc = (int*)(ws + 256 * KB);
    float* cw = (float*)(ws + 768 * KB);
    float* util = (float*)(ws + 1280 * KB);
    unsigned char* x8 = (unsigned char*)(ws + 2 * MB);       // 1MB fp8
    unsigned char* wt_in8 = (unsigned char*)(ws + 4 * MB);                 // 64KB
    unsigned char* wt_mid8 = (unsigned char*)(ws + 4 * MB + 64 * KB);      // 256KB
    unsigned char* wt_out8 = (unsigned char*)(ws + 4 * MB + 320 * KB);     // 256KB
    unsigned char* wt_fc18 = (unsigned char*)(ws + 4 * MB + 576 * KB);     // 256KB
    unsigned char* wt_fc2p8 = (unsigned char*)(ws + 4 * MB + 832 * KB);    // 64KB padded
    unsigned char* qkv1_8 = (unsigned char*)(ws + 6 * MB);   // 1.5MB
    unsigned char* qkv2_8 = (unsigned char*)(ws + 8 * MB);   // 3MB
    unsigned char* qkv3_8 = (unsigned char*)(ws + 11 * MB);  // 1.5MB
    unsigned char* h8 = (unsigned char*)(ws + 21 * MB);      // 4MB fp8
    unsigned char* t1_8 = (unsigned char*)(ws + 25 * MB);    // 24MB
    unsigned char* t2_8 = (unsigned char*)(ws + 49 * MB);    // 24MB
    unsigned char* u8 = (unsigned char*)(ws + 73 * MB);      // 4MB (agg output)
    unsigned char* g8 = (unsigned char*)(ws + 77 * MB);      // 4MB
    unsigned char* q8 = (unsigned char*)(ws + 81 * MB);      // 4MB
    unsigned char* k8 = (unsigned char*)(ws + 85 * MB);      // 4MB (q8+4MB)
    unsigned char* vt8 = (unsigned char*)(ws + 89 * MB);     // 4MB (q8+8MB)
    unsigned char* x2_8 = (unsigned char*)(ws + 93 * MB);    // 4MB (ends 97MB)
    float* h32 = (float*)(ws + 2 * MB);                      // alias of x8, end of net

    // --- fused prep (cast + cnt zero + all weight transposes) ---
    k_prep<<<8096, 256, 0, stream>>>(x, x8, cnt, w_in, wt_in8, w_mid, wt_mid8,
                                     w_out, wt_out8, fc1_w, wt_fc18, fc2_w, wt_fc2p8,
                                     qkv1_w, qkv1_8, qkv2_w, qkv2_8, qkv3_w, qkv3_8);

    // --- degree + CSR build ---
    k_count<<<EE / 256, 256, 0, stream>>>(ei, cnt);
    k_scan<<<1, 1024, 0, stream>>>(cnt, off, pos, dinv);
    k_fill<<<EE / 256, 256, 0, stream>>>(ei, dinv, pos, csrc, cw);

    auto layer = [&](const unsigned char* hin8, const unsigned char* wt8,
                     const float* b, int Kin) {
        // GCN (agg-first, linear commute): u = agg(h); g = tanh(u @ W + b)
        agg8<<<NN, 256, 0, stream>>>(hin8, off, csrc, cw, dinv, u8, Kin);
        gemm_mx<2, 10, 1><<<dim3(4, 64), 256, 0, stream>>>(
            u8, wt8, b, g8, Kin, Kin, Kin, 512, 512, 0, 0, 0, 0,
            nullptr, nullptr);
        // qkv MLP (MX fp8): qkv1 wide M=3072, qkv2 z=3, qkv3 z=3 (v transposed)
        gemm_mx<1, 10, 1><<<dim3(24, 64), 256, 0, stream>>>(
            g8, qkv1_8, qkv1_b, t1_8, 512, 512, 512, 3072, 3072, 0, 0, 0, 0,
            nullptr, nullptr);
        gemm_mx<1, 10, 1><<<dim3(8, 64, 3), 256, 0, stream>>>(
            t1_8, qkv2_8, qkv2_b, t2_8, 1024, 3072, 1024, 3072, 1024,
            1024, 1048576, 1024, 1024, nullptr, nullptr);
        gemm_mx<1, 3, 1><<<dim3(4, 64, 3), 256, 0, stream>>>(
            t2_8, qkv3_8, qkv3_b, q8, 1024, 3072, 1024, 512, 512,
            1024, 524288, 4194304, 512, nullptr, nullptr);
        // fused attention (4 blocks per doc-pair block): -> h8 (fp8)
        attn_fused<<<4 * NDOC, 256, 0, stream>>>(q8, k8, vt8, h8);
    };

    layer(x8, wt_in8, b_in, F_IN);
    layer(h8, wt_mid8, b_mid, DD);
    layer(h8, wt_mid8, b_mid, DD);
    layer(h8, wt_out8, b_out, DD);

    // final FCs (MX fp8) + pool + pairwise sigmoid
    gemm_mx<2, 10, 1><<<dim3(4, 64), 256, 0, stream>>>(
        h8, wt_fc18, fc1_b, x2_8, 512, 512, 512, 512, 512, 0, 0, 0, 0,
        nullptr, nullptr);
    gemm_mx<2, 20, 0><<<dim3(1, 64), 256, 0, stream>>>(
        x2_8, wt_fc2p8, fc2_b, util, 512, 512, 512, 32, 32, 0, 0, 0, 0,
        fc3_w, fc3_b);
    final_out<<<1, 64, 0, stream>>>(util, idx_a, idx_b, out);
}